// Round 9
// baseline (845.100 us; speedup 1.0000x reference)
//
#include <hip/hip_runtime.h>

#define NATOM 65536
#define MNBR 12
#define NMROW (NATOM*MNBR)      // 786432
#define ORIG 92
#define NBRF 41
#define AF 64
#define HF 128
#define NCRYS 1024
#define EPSBN 1e-5f
#define NBP 48                  // padded edge width (bf16)
#define CGRID 2048
#define NTASK 16384             // 48-row tasks; 8 per block exactly

typedef __attribute__((ext_vector_type(8))) short short8;
typedef __attribute__((ext_vector_type(4))) float floatx4;

__device__ __forceinline__ float softplusf_(float x){
    return fmaxf(x,0.f) + __logf(1.f + __expf(-fabsf(x)));
}
__device__ __forceinline__ float sigmoidf_(float x){
    return __builtin_amdgcn_rcpf(1.f + __expf(-x));
}
__device__ __forceinline__ short f2bf(float x){
    unsigned u = __float_as_uint(x);
    u += 0x7fffu + ((u >> 16) & 1u);   // RNE
    return (short)(u >> 16);
}
__device__ __forceinline__ unsigned packbf(float f, float g){
    return (unsigned)(unsigned short)f2bf(f) | ((unsigned)(unsigned short)f2bf(g) << 16);
}

// ---------------- embedding: afea = atom_fea @ emb_w + emb_b ----------------
__global__ void k_embed(const float* __restrict__ atom_fea, const float* __restrict__ emb_w,
                        const float* __restrict__ emb_b, float* __restrict__ afea,
                        short* __restrict__ abf)
{
    __shared__ float wl[ORIG*AF];
    __shared__ float bl[AF];
    __shared__ float rows[4*ORIG];
    int tid = threadIdx.x;
    for (int i = tid; i < ORIG*AF; i += 256) wl[i] = emb_w[i];
    if (tid < AF) bl[tid] = emb_b[tid];
    __syncthreads();
    for (int t = blockIdx.x; t < NATOM/4; t += gridDim.x) {
        for (int i = tid; i < 4*ORIG; i += 256) rows[i] = atom_fea[t*4*ORIG + i];
        __syncthreads();
        int r = tid >> 6, c = tid & 63;
        float acc = bl[c];
        const float* rp = &rows[r*ORIG];
        #pragma unroll 4
        for (int k = 0; k < ORIG; ++k) acc += rp[k] * wl[k*AF + c];
        int n = t*4 + r;
        afea[n*AF + c] = acc;
        abf[n*AF + c] = f2bf(acc);
        __syncthreads();
    }
}

// ------------- one-time: nbr_fea fp32 [NM][41] -> bf16 padded [NM][48] -------------
// nbr_fea read exactly once ever -> non-temporal loads (keeps LLC for nbf/abf;
// this is what fixed the 197us cold first conv). nbf writes stay normal (LLC-resident).
__global__ void k_prep_nbr(const float* __restrict__ nbr_fea, short* __restrict__ nbf)
{
    int g = blockIdx.x*256 + threadIdx.x;   // NMROW*6 threads
    int row = g / 6, c = g % 6;
    const float* src = nbr_fea + (long)row*NBRF + c*8;
    short8 v = {0,0,0,0,0,0,0,0};
    if (c < 5) {
        #pragma unroll
        for (int j = 0; j < 8; ++j) v[j] = f2bf(__builtin_nontemporal_load(src + j));
    } else {
        v[0] = f2bf(__builtin_nontemporal_load(src));   // k=40 only
    }
    *(short8*)(nbf + (long)g*8) = v;
}

// ------------- per-layer: W fp32 [169][128] -> bf16 fragments [ks][q][c][j] -------------
__global__ void k_prep_w(const float* __restrict__ W, short* __restrict__ wt2)
{
    int g = blockIdx.x*256 + threadIdx.x;   // 24576 threads
    int j = g & 7, c = (g >> 3) & 127, q = (g >> 10) & 3, ks = g >> 12;
    int k = ks*32 + q*8 + j;
    wt2[g] = (k < 169) ? f2bf(W[k*128 + c]) : (short)0;
}

// ---------------- conv GEMM: gated = [self|nbr|edge] @ W + b ----------------
// Task = 48 rows (4 atoms) x 128 ch; block's 4 waves share rows, wave owns 16
// paired channels (filt cf = wave*16+l15, core cf+64). Double-buffered LDS
// staging, software-pipelined (idx prefetched 2 ahead, gathers at TOP of iter).
// launch_bounds(256,3) / 84 VGPR. Schedule is at its local optimum (measured:
// deep prefetch spills; bottom-issue 121us; no-drain barrier 117us).
// TASK MAPPING: block bt owns CONTIGUOUS tasks [8*bt, 8*bt+8). Measured
// invariant: beyond-L2 read rate pinned at ~0.9 TB/s across all configs ->
// scattered-stream wall. Contiguous tasks give each block one sequential
// 36.8 KB nbf window (8x fewer concurrent DRAM streams, same bytes).
// MODE 0: stats1 only (pass1). MODE 1: BN1+gate+m-sum (pass2).
// MODE 2: stats1 + packed bf16 gated pairs -> gpair (single-GEMM path, unused).
template<int MODE>
__global__ __launch_bounds__(256, 3)
void k_conv(const short* __restrict__ abf, const short* __restrict__ nbf,
            const int* __restrict__ nbr_idx, const short* __restrict__ wt2,
            const float* __restrict__ bias,
            float* __restrict__ stats1, const float* __restrict__ bn1ss,
            float* __restrict__ nsum, float* __restrict__ stats2,
            unsigned* __restrict__ gpair)
{
    __shared__ __align__(16) short stg[2][6432];
    __shared__ float pbuf[(MODE==1) ? 4*12*17 : 4];

    int tid = threadIdx.x;
    int lane = tid & 63, wave = tid >> 6;
    int l15 = lane & 15, q = lane >> 4;
    int cf = wave*16 + l15;
    int cc = 64 + cf;

    short8 wf[6][2];
    #pragma unroll
    for (int ks = 0; ks < 6; ++ks) {
        wf[ks][0] = *(const short8*)(wt2 + ((ks*4+q)*128 + cf)*8);
        wf[ks][1] = *(const short8*)(wt2 + ((ks*4+q)*128 + cc)*8);
    }
    float bs0 = bias[cf], bs1 = bias[cc];
    float sc0=0.f, sh0=0.f, sc1=0.f, sh1=0.f;
    if (MODE==1) { sc0=bn1ss[cf]; sh0=bn1ss[128+cf]; sc1=bn1ss[cc]; sh1=bn1ss[128+cc]; }

    int kind[3], ldso[3], nrow[3]; long gco[3];
    #pragma unroll
    for (int s = 0; s < 3; ++s) {
        int i = tid + s*256;
        if (i < 384)      { kind[s]=0; int row=i>>3, c=i&7; nrow[s]=row; ldso[s]=row*72+c*8; gco[s]=c*8; }
        else if (i < 672) { kind[s]=1; int j=i-384; int row=j/6, c=j%6; nrow[s]=0; ldso[s]=3456+row*56+c*8; gco[s]=row*48+c*8; }
        else if (i < 704) { kind[s]=2; int j=i-672; int a=j>>3, c=j&7; nrow[s]=0; ldso[s]=6144+a*72+c*8; gco[s]=a*64+c*8; }
        else              { kind[s]=3; nrow[s]=0; ldso[s]=0; gco[s]=0; }
    }
    int art[3], nvo[3], evo[3], svo[3];
    #pragma unroll
    for (int rt = 0; rt < 3; ++rt) {
        int r = rt*16 + l15;
        art[rt] = r/12;
        nvo[rt] = r*72 + q*8;
        evo[rt] = 3456 + r*56 + q*8;
        svo[rt] = 6144 + art[rt]*72 + q*8;
    }

    float s_acc[2]={0.f,0.f}, s2_acc[2]={0.f,0.f};
    float st2s = 0.f, st2q = 0.f;
    const short8 zf = {0,0,0,0,0,0,0,0};
    float* pb = pbuf + ((MODE==1) ? wave*(12*17) : 0);
    const int t0 = blockIdx.x * 8;          // first task of this block (contiguous)

    int nid[3];
    short8 hold[3];
    #pragma unroll
    for (int s = 0; s < 3; ++s)
        if (kind[s]==0) nid[s] = nbr_idx[t0*48 + nrow[s]];
    #pragma unroll
    for (int s = 0; s < 3; ++s) {
        if (kind[s]==0)      hold[s] = *(const short8*)(abf + (unsigned)nid[s]*64u + gco[s]);
        else if (kind[s]==1) hold[s] = *(const short8*)(nbf + (long)t0*2304 + gco[s]);
        else if (kind[s]==2) hold[s] = *(const short8*)(abf + (unsigned)t0*256u + gco[s]);
    }
    #pragma unroll
    for (int s = 0; s < 3; ++s)
        if (kind[s]==0) nid[s] = nbr_idx[(t0+1)*48 + nrow[s]];
    #pragma unroll
    for (int s = 0; s < 3; ++s)
        if (kind[s] < 3) *(short8*)(&stg[0][0] + ldso[s]) = hold[s];
    __syncthreads();

    #pragma unroll 2
    for (int k = 0; k < 8; ++k) {
        int b = t0 + k;
        if (k < 7) {
            int bn = b + 1;
            #pragma unroll
            for (int s = 0; s < 3; ++s) {
                if (kind[s]==0)      hold[s] = *(const short8*)(abf + (unsigned)nid[s]*64u + gco[s]);
                else if (kind[s]==1) hold[s] = *(const short8*)(nbf + (long)bn*2304 + gco[s]);
                else if (kind[s]==2) hold[s] = *(const short8*)(abf + (unsigned)bn*256u + gco[s]);
            }
            if (k < 6) {
                #pragma unroll
                for (int s = 0; s < 3; ++s)
                    if (kind[s]==0) nid[s] = nbr_idx[(bn+1)*48 + nrow[s]];
            }
        }

        const short* sb = &stg[k & 1][0];
        floatx4 acc[3][2];
        #pragma unroll
        for (int rt=0; rt<3; ++rt) {
            acc[rt][0] = (floatx4){bs0,bs0,bs0,bs0};
            acc[rt][1] = (floatx4){bs1,bs1,bs1,bs1};
        }
        #pragma unroll
        for (int rt = 0; rt < 3; ++rt) {
            short8 sv0 = *(const short8*)(sb + svo[rt]);
            short8 sv1 = *(const short8*)(sb + svo[rt] + 32);
            short8 nv0 = *(const short8*)(sb + nvo[rt]);
            short8 nv1 = *(const short8*)(sb + nvo[rt] + 32);
            short8 ev0 = *(const short8*)(sb + evo[rt]);
            short8 ev1 = (q < 2) ? *(const short8*)(sb + evo[rt] + 32) : zf;
            #pragma unroll
            for (int ct = 0; ct < 2; ++ct) {
                acc[rt][ct] = __builtin_amdgcn_mfma_f32_16x16x32_bf16(sv0, wf[0][ct], acc[rt][ct], 0,0,0);
                acc[rt][ct] = __builtin_amdgcn_mfma_f32_16x16x32_bf16(sv1, wf[1][ct], acc[rt][ct], 0,0,0);
                acc[rt][ct] = __builtin_amdgcn_mfma_f32_16x16x32_bf16(nv0, wf[2][ct], acc[rt][ct], 0,0,0);
                acc[rt][ct] = __builtin_amdgcn_mfma_f32_16x16x32_bf16(nv1, wf[3][ct], acc[rt][ct], 0,0,0);
                acc[rt][ct] = __builtin_amdgcn_mfma_f32_16x16x32_bf16(ev0, wf[4][ct], acc[rt][ct], 0,0,0);
                acc[rt][ct] = __builtin_amdgcn_mfma_f32_16x16x32_bf16(ev1, wf[5][ct], acc[rt][ct], 0,0,0);
            }
        }

        if (MODE != 1) {
            #pragma unroll
            for (int ct=0; ct<2; ++ct)
                #pragma unroll
                for (int rt=0; rt<3; ++rt)
                    #pragma unroll
                    for (int r=0; r<4; ++r) {
                        float v = acc[rt][ct][r];
                        s_acc[ct] += v; s2_acc[ct] += v*v;
                    }
        }
        if (MODE == 2) {
            #pragma unroll
            for (int rt=0; rt<3; ++rt) {
                unsigned base = (unsigned)(b*48 + rt*16 + q*4)*64u + (unsigned)(wave*16 + l15);
                #pragma unroll
                for (int r=0; r<4; ++r)
                    gpair[base + (unsigned)r*64u] = packbf(acc[rt][0][r], acc[rt][1][r]);
            }
        }
        if (MODE == 1) {
            #pragma unroll
            for (int rt=0; rt<3; ++rt) {
                float part = 0.f;
                #pragma unroll
                for (int r=0; r<4; ++r) {
                    float f = acc[rt][0][r]*sc0 + sh0;
                    float g = acc[rt][1][r]*sc1 + sh1;
                    part += sigmoidf_(f) * softplusf_(g);
                }
                pb[(rt*4+q)*17 + l15] = part;
            }
            int a = lane >> 4, c16 = lane & 15;
            float s = pb[(3*a+0)*17 + c16] + pb[(3*a+1)*17 + c16] + pb[(3*a+2)*17 + c16];
            nsum[(b*4 + a)*AF + wave*16 + c16] = s;
            st2s += s; st2q += s*s;
        }

        if (k < 7) {
            short* db = &stg[(k + 1) & 1][0];
            #pragma unroll
            for (int s = 0; s < 3; ++s)
                if (kind[s] < 3) *(short8*)(db + ldso[s]) = hold[s];
        }
        __syncthreads();
    }

    if (MODE != 1) {
        #pragma unroll
        for (int ct=0; ct<2; ++ct) {
            float s = s_acc[ct], s2 = s2_acc[ct];
            s  += __shfl_xor(s, 16);  s  += __shfl_xor(s, 32);
            s2 += __shfl_xor(s2, 16); s2 += __shfl_xor(s2, 32);
            if (q == 0) {
                int c = ct ? cc : cf;
                atomicAdd(&stats1[c], s);
                atomicAdd(&stats1[128 + c], s2);
            }
        }
    } else {
        st2s += __shfl_xor(st2s, 16); st2s += __shfl_xor(st2s, 32);
        st2q += __shfl_xor(st2q, 16); st2q += __shfl_xor(st2q, 32);
        if (q == 0) {
            atomicAdd(&stats2[cf], st2s);
            atomicAdd(&stats2[64 + cf], st2q);
        }
    }
}

// -------- elementwise pass 2 (big-ws path, unused by launcher now) --------
__global__ __launch_bounds__(256, 4)
void k_gate(const unsigned* __restrict__ gpair, const float* __restrict__ stats1,
            const float* __restrict__ g1, const float* __restrict__ b1,
            float* __restrict__ nsum, float* __restrict__ stats2)
{
    __shared__ float red[2][4][64];
    int tid = threadIdx.x;
    int lane = tid & 63, wave = tid >> 6;
    float mf = stats1[lane]       * (1.f/NMROW);
    float vf = stats1[128+lane]   * (1.f/NMROW) - mf*mf;
    float scf = g1[lane] * rsqrtf(vf + EPSBN);
    float shf = b1[lane] - mf*scf;
    float mc = stats1[64+lane]    * (1.f/NMROW);
    float vc = stats1[192+lane]   * (1.f/NMROW) - mc*mc;
    float scc = g1[64+lane] * rsqrtf(vc + EPSBN);
    float shc = b1[64+lane] - mc*scc;
    float st2s = 0.f, st2q = 0.f;
    int a0 = blockIdx.x*64 + wave;
    for (int j = 0; j < 16; ++j) {
        int atom = a0 + j*4;
        const unsigned* gp = gpair + (unsigned)atom*12u*64u + lane;
        unsigned u[12];
        #pragma unroll
        for (int i = 0; i < 12; ++i) u[i] = gp[i*64];
        float s = 0.f;
        #pragma unroll
        for (int i = 0; i < 12; ++i) {
            float f = __uint_as_float(u[i] << 16);
            float g = __uint_as_float(u[i] & 0xffff0000u);
            f = f*scf + shf;
            g = g*scc + shc;
            s += sigmoidf_(f) * softplusf_(g);
        }
        nsum[atom*AF + lane] = s;
        st2s += s; st2q += s*s;
    }
    red[0][wave][lane] = st2s;
    red[1][wave][lane] = st2q;
    __syncthreads();
    if (tid < 64) {
        float s  = red[0][0][tid] + red[0][1][tid] + red[0][2][tid] + red[0][3][tid];
        float s2 = red[1][0][tid] + red[1][1][tid] + red[1][2][tid] + red[1][3][tid];
        atomicAdd(&stats2[tid], s);
        atomicAdd(&stats2[64 + tid], s2);
    }
}

__global__ void k_bn1fin(const float* __restrict__ stats1, const float* __restrict__ g,
                         const float* __restrict__ b, float* __restrict__ bn1ss)
{
    int c = threadIdx.x;
    float mean = stats1[c] * (1.f/NMROW);
    float var  = stats1[128+c] * (1.f/NMROW) - mean*mean;
    float scale = g[c] * rsqrtf(var + EPSBN);
    bn1ss[c] = scale;
    bn1ss[128+c] = b[c] - mean*scale;
}

__global__ void k_update(float* __restrict__ afea, short* __restrict__ abf,
                         const float* __restrict__ nsum,
                         const float* __restrict__ stats2,
                         const float* __restrict__ g2, const float* __restrict__ b2)
{
    int g = blockIdx.x*256 + threadIdx.x;   // 16384 blocks
    int c = g & 63;
    float mean = stats2[c] * (1.f/NATOM);
    float var  = stats2[64+c] * (1.f/NATOM) - mean*mean;
    float scale = g2[c]*rsqrtf(var + EPSBN);
    float shift = b2[c] - mean*scale;
    float ns = nsum[g]*scale + shift;
    float a = afea[g];
    float v = softplusf_(a + ns) + a;       // afea == identity invariant
    afea[g] = v; abf[g] = f2bf(v);
}

__global__ void k_pool(const float* __restrict__ afea, const int* __restrict__ cidx,
                       float* __restrict__ pool, float* __restrict__ cnt)
{
    int g = blockIdx.x*256 + threadIdx.x;   // 1024 blocks
    int c = g & 63; int chunk = g >> 6;     // 4096 chunks x 16 atoms
    float run = 0.f, rc = 0.f; int cur = -1;
    for (int i = 0; i < 16; ++i) {
        int a = chunk*16 + i;
        int cr = cidx[a];
        float v = afea[a*64 + c];
        if (cr != cur) {
            if (cur >= 0) { atomicAdd(&pool[cur*64+c], run); if (c==0) atomicAdd(&cnt[cur], rc); }
            run = 0.f; rc = 0.f; cur = cr;
        }
        run += v; rc += 1.f;
    }
    atomicAdd(&pool[cur*64+c], run); if (c==0) atomicAdd(&cnt[cur], rc);
}

__global__ void k_head(const float* __restrict__ pool, const float* __restrict__ cnt,
                       const float* __restrict__ fc1w, const float* __restrict__ fc1b,
                       const float* __restrict__ o1w, const float* __restrict__ o1b,
                       const float* __restrict__ o2w, const float* __restrict__ o2b,
                       float* __restrict__ dout)
{
    __shared__ float spv[64], crys[128], h1[64];
    int b = blockIdx.x, tid = threadIdx.x;
    if (tid < 64) {
        float ct = fmaxf(cnt[b], 1.f);
        spv[tid] = softplusf_(pool[b*64+tid] / ct);
    }
    __syncthreads();
    float a = fc1b[tid];
    for (int k = 0; k < 64; ++k) a += spv[k] * fc1w[k*128 + tid];
    float v = softplusf_(a);
    crys[tid] = v;
    dout[NCRYS + b*128 + tid] = v;
    __syncthreads();
    if (tid < 64) {
        float a2 = o1b[tid];
        for (int k = 0; k < 128; ++k) a2 += crys[k] * o1w[k*64 + tid];
        h1[tid] = softplusf_(a2) * o2w[tid];
    }
    __syncthreads();
    if (tid == 0) {
        float s = o2b[0];
        for (int j = 0; j < 64; ++j) s += h1[j];
        dout[b] = s;
    }
}

extern "C" void kernel_launch(void* const* d_in, const int* in_sizes, int n_in,
                              void* d_out, int out_size, void* d_ws, size_t ws_size,
                              hipStream_t stream)
{
    const float* atom_fea = (const float*)d_in[0];
    const float* nbr_fea  = (const float*)d_in[1];
    const int*   nbr_idx  = (const int*)d_in[2];
    const int*   cidx     = (const int*)d_in[3];
    const float* emb_w    = (const float*)d_in[4];
    const float* emb_b    = (const float*)d_in[5];
    const float* cfw      = (const float*)d_in[6];
    const float* cfb      = (const float*)d_in[7];
    const float* bn1g     = (const float*)d_in[8];
    const float* bn1b     = (const float*)d_in[9];
    const float* bn2g     = (const float*)d_in[10];
    const float* bn2b     = (const float*)d_in[11];
    const float* fc1w     = (const float*)d_in[12];
    const float* fc1b     = (const float*)d_in[13];
    const float* o1w      = (const float*)d_in[14];
    const float* o1b      = (const float*)d_in[15];
    const float* o2w      = (const float*)d_in[16];
    const float* o2b      = (const float*)d_in[17];

    float* ws    = (float*)d_ws;
    float* afea  = ws;                         // 16 MB
    float* nsum  = ws + 4194304;               // 16 MB
    short* abf   = (short*)(ws + 8388608);     // 8 MB
    short* nbf   = (short*)(ws + 10485760);    // 75.5 MB
    short* wt2   = (short*)(ws + 29360128);    // 48 KB
    float* stats = ws + 29372416;              // 3 x 640
    float* pool  = ws + 29374336;              // 256 KB
    float* cnt   = ws + 29439872;              // 4 KB

    // 2-PASS PATH: equal to the gpair path (measured 823 vs 811) but with
    // minimal conv FETCH (83 MB, dominated by the compulsory nbf stream) --
    // the cleanest substrate for the stream-contiguity experiment.
    hipMemsetAsync(stats, 0, (1920 + 65536 + 1024)*sizeof(float), stream);

    k_prep_nbr<<<(NMROW*6)/256, 256, 0, stream>>>(nbr_fea, nbf);
    k_embed<<<2048, 256, 0, stream>>>(atom_fea, emb_w, emb_b, afea, abf);

    for (int L = 0; L < 3; ++L) {
        float* st1 = stats + L*640;
        float* ss  = st1 + 256;
        float* st2 = st1 + 512;
        k_prep_w<<<96, 256, 0, stream>>>(cfw + L*169*128, wt2);
        k_conv<0><<<CGRID, 256, 0, stream>>>(abf, nbf, nbr_idx, wt2, cfb + L*128,
                                             st1, nullptr, nullptr, nullptr, nullptr);
        k_bn1fin<<<1, 128, 0, stream>>>(st1, bn1g + L*128, bn1b + L*128, ss);
        k_conv<1><<<CGRID, 256, 0, stream>>>(abf, nbf, nbr_idx, wt2, cfb + L*128,
                                             nullptr, ss, nsum, st2, nullptr);
        k_update<<<16384, 256, 0, stream>>>(afea, abf, nsum, st2, bn2g + L*64, bn2b + L*64);
    }
    k_pool<<<1024, 256, 0, stream>>>(afea, cidx, pool, cnt);
    k_head<<<NCRYS, 128, 0, stream>>>(pool, cnt, fc1w, fc1b, o1w, o1b, o2w, o2b, (float*)d_out);
}

// Round 10
// 810.400 us; speedup vs baseline: 1.0428x; 1.0428x over previous
//
#include <hip/hip_runtime.h>

#define NATOM 65536
#define MNBR 12
#define NMROW (NATOM*MNBR)      // 786432
#define ORIG 92
#define NBRF 41
#define AF 64
#define HF 128
#define NCRYS 1024
#define EPSBN 1e-5f
#define NBP 48                  // padded edge width (bf16)
#define CGRID 2048
#define NTASK 16384             // 48-row tasks; 8 per block exactly

typedef __attribute__((ext_vector_type(8))) short short8;
typedef __attribute__((ext_vector_type(4))) float floatx4;

__device__ __forceinline__ float softplusf_(float x){
    return fmaxf(x,0.f) + __logf(1.f + __expf(-fabsf(x)));
}
__device__ __forceinline__ float sigmoidf_(float x){
    return __builtin_amdgcn_rcpf(1.f + __expf(-x));
}
__device__ __forceinline__ short f2bf(float x){
    unsigned u = __float_as_uint(x);
    u += 0x7fffu + ((u >> 16) & 1u);   // RNE
    return (short)(u >> 16);
}
__device__ __forceinline__ unsigned packbf(float f, float g){
    return (unsigned)(unsigned short)f2bf(f) | ((unsigned)(unsigned short)f2bf(g) << 16);
}

// ---------------- embedding: afea = atom_fea @ emb_w + emb_b ----------------
__global__ void k_embed(const float* __restrict__ atom_fea, const float* __restrict__ emb_w,
                        const float* __restrict__ emb_b, float* __restrict__ afea,
                        short* __restrict__ abf)
{
    __shared__ float wl[ORIG*AF];
    __shared__ float bl[AF];
    __shared__ float rows[4*ORIG];
    int tid = threadIdx.x;
    for (int i = tid; i < ORIG*AF; i += 256) wl[i] = emb_w[i];
    if (tid < AF) bl[tid] = emb_b[tid];
    __syncthreads();
    for (int t = blockIdx.x; t < NATOM/4; t += gridDim.x) {
        for (int i = tid; i < 4*ORIG; i += 256) rows[i] = atom_fea[t*4*ORIG + i];
        __syncthreads();
        int r = tid >> 6, c = tid & 63;
        float acc = bl[c];
        const float* rp = &rows[r*ORIG];
        #pragma unroll 4
        for (int k = 0; k < ORIG; ++k) acc += rp[k] * wl[k*AF + c];
        int n = t*4 + r;
        afea[n*AF + c] = acc;
        abf[n*AF + c] = f2bf(acc);
        __syncthreads();
    }
}

// ------------- one-time: nbr_fea fp32 [NM][41] -> bf16 padded [NM][48] -------------
// nbr_fea read exactly once ever -> non-temporal loads (keeps LLC for nbf/abf;
// this is what fixed the 197us cold first conv). nbf writes stay normal (LLC-resident).
__global__ void k_prep_nbr(const float* __restrict__ nbr_fea, short* __restrict__ nbf)
{
    int g = blockIdx.x*256 + threadIdx.x;   // NMROW*6 threads
    int row = g / 6, c = g % 6;
    const float* src = nbr_fea + (long)row*NBRF + c*8;
    short8 v = {0,0,0,0,0,0,0,0};
    if (c < 5) {
        #pragma unroll
        for (int j = 0; j < 8; ++j) v[j] = f2bf(__builtin_nontemporal_load(src + j));
    } else {
        v[0] = f2bf(__builtin_nontemporal_load(src));   // k=40 only
    }
    *(short8*)(nbf + (long)g*8) = v;
}

// ------------- per-layer: W fp32 [169][128] -> bf16 fragments [ks][q][c][j] -------------
__global__ void k_prep_w(const float* __restrict__ W, short* __restrict__ wt2)
{
    int g = blockIdx.x*256 + threadIdx.x;   // 24576 threads
    int j = g & 7, c = (g >> 3) & 127, q = (g >> 10) & 3, ks = g >> 12;
    int k = ks*32 + q*8 + j;
    wt2[g] = (k < 169) ? f2bf(W[k*128 + c]) : (short)0;
}

// ---------------- conv GEMM: gated = [self|nbr|edge] @ W + b ----------------
// Task = 48 rows (4 atoms) x 128 ch; block's 4 waves share rows, wave owns 16
// paired channels (filt cf = wave*16+l15, core cf+64). Double-buffered LDS
// staging, software-pipelined (idx prefetched 2 ahead, gathers at TOP of iter).
// launch_bounds(256,3) / 84 VGPR: measured local optimum. Session evidence:
//  - (256,4) forces 64-VGPR bin -> spills (FETCH 84->455MB, 314us)  [r2]
//  - bottom-of-iter gather issue -> 121us (exposed at barrier drain) [r5]
//  - lgkmcnt-only barrier -> 117us (scheduler constraint)            [r6]
//  - contiguous task mapping -> 93.5us in 2-pass (stream theory dead)[r9]
//  - occupancy tracks VGPR bin exactly (27%@84 vs 44%@64): latency
//    plateau is structural at this register budget.
// MODE 0: stats1 only (fallback pass1). MODE 1: BN1+gate+m-sum (fallback pass2).
// MODE 2: stats1 + packed bf16 gated pairs -> gpair (single-GEMM path).
template<int MODE>
__global__ __launch_bounds__(256, 3)
void k_conv(const short* __restrict__ abf, const short* __restrict__ nbf,
            const int* __restrict__ nbr_idx, const short* __restrict__ wt2,
            const float* __restrict__ bias,
            float* __restrict__ stats1, const float* __restrict__ bn1ss,
            float* __restrict__ nsum, float* __restrict__ stats2,
            unsigned* __restrict__ gpair)
{
    __shared__ __align__(16) short stg[2][6432];
    __shared__ float pbuf[(MODE==1) ? 4*12*17 : 4];

    int tid = threadIdx.x;
    int lane = tid & 63, wave = tid >> 6;
    int l15 = lane & 15, q = lane >> 4;
    int cf = wave*16 + l15;
    int cc = 64 + cf;

    short8 wf[6][2];
    #pragma unroll
    for (int ks = 0; ks < 6; ++ks) {
        wf[ks][0] = *(const short8*)(wt2 + ((ks*4+q)*128 + cf)*8);
        wf[ks][1] = *(const short8*)(wt2 + ((ks*4+q)*128 + cc)*8);
    }
    float bs0 = bias[cf], bs1 = bias[cc];
    float sc0=0.f, sh0=0.f, sc1=0.f, sh1=0.f;
    if (MODE==1) { sc0=bn1ss[cf]; sh0=bn1ss[128+cf]; sc1=bn1ss[cc]; sh1=bn1ss[128+cc]; }

    int kind[3], ldso[3], nrow[3]; long gco[3];
    #pragma unroll
    for (int s = 0; s < 3; ++s) {
        int i = tid + s*256;
        if (i < 384)      { kind[s]=0; int row=i>>3, c=i&7; nrow[s]=row; ldso[s]=row*72+c*8; gco[s]=c*8; }
        else if (i < 672) { kind[s]=1; int j=i-384; int row=j/6, c=j%6; nrow[s]=0; ldso[s]=3456+row*56+c*8; gco[s]=row*48+c*8; }
        else if (i < 704) { kind[s]=2; int j=i-672; int a=j>>3, c=j&7; nrow[s]=0; ldso[s]=6144+a*72+c*8; gco[s]=a*64+c*8; }
        else              { kind[s]=3; nrow[s]=0; ldso[s]=0; gco[s]=0; }
    }
    int art[3], nvo[3], evo[3], svo[3];
    #pragma unroll
    for (int rt = 0; rt < 3; ++rt) {
        int r = rt*16 + l15;
        art[rt] = r/12;
        nvo[rt] = r*72 + q*8;
        evo[rt] = 3456 + r*56 + q*8;
        svo[rt] = 6144 + art[rt]*72 + q*8;
    }

    float s_acc[2]={0.f,0.f}, s2_acc[2]={0.f,0.f};
    float st2s = 0.f, st2q = 0.f;
    const short8 zf = {0,0,0,0,0,0,0,0};
    float* pb = pbuf + ((MODE==1) ? wave*(12*17) : 0);
    const int bt = blockIdx.x;

    int nid[3];
    short8 hold[3];
    #pragma unroll
    for (int s = 0; s < 3; ++s)
        if (kind[s]==0) nid[s] = nbr_idx[bt*48 + nrow[s]];
    #pragma unroll
    for (int s = 0; s < 3; ++s) {
        if (kind[s]==0)      hold[s] = *(const short8*)(abf + (unsigned)nid[s]*64u + gco[s]);
        else if (kind[s]==1) hold[s] = *(const short8*)(nbf + (long)bt*2304 + gco[s]);
        else if (kind[s]==2) hold[s] = *(const short8*)(abf + (unsigned)bt*256u + gco[s]);
    }
    #pragma unroll
    for (int s = 0; s < 3; ++s)
        if (kind[s]==0) nid[s] = nbr_idx[(bt+CGRID)*48 + nrow[s]];
    #pragma unroll
    for (int s = 0; s < 3; ++s)
        if (kind[s] < 3) *(short8*)(&stg[0][0] + ldso[s]) = hold[s];
    __syncthreads();

    #pragma unroll 2
    for (int k = 0; k < 8; ++k) {
        int b = bt + k*CGRID;
        if (k < 7) {
            int bn = b + CGRID;
            #pragma unroll
            for (int s = 0; s < 3; ++s) {
                if (kind[s]==0)      hold[s] = *(const short8*)(abf + (unsigned)nid[s]*64u + gco[s]);
                else if (kind[s]==1) hold[s] = *(const short8*)(nbf + (long)bn*2304 + gco[s]);
                else if (kind[s]==2) hold[s] = *(const short8*)(abf + (unsigned)bn*256u + gco[s]);
            }
            if (k < 6) {
                #pragma unroll
                for (int s = 0; s < 3; ++s)
                    if (kind[s]==0) nid[s] = nbr_idx[(bn+CGRID)*48 + nrow[s]];
            }
        }

        const short* sb = &stg[k & 1][0];
        floatx4 acc[3][2];
        #pragma unroll
        for (int rt=0; rt<3; ++rt) {
            acc[rt][0] = (floatx4){bs0,bs0,bs0,bs0};
            acc[rt][1] = (floatx4){bs1,bs1,bs1,bs1};
        }
        #pragma unroll
        for (int rt = 0; rt < 3; ++rt) {
            short8 sv0 = *(const short8*)(sb + svo[rt]);
            short8 sv1 = *(const short8*)(sb + svo[rt] + 32);
            short8 nv0 = *(const short8*)(sb + nvo[rt]);
            short8 nv1 = *(const short8*)(sb + nvo[rt] + 32);
            short8 ev0 = *(const short8*)(sb + evo[rt]);
            short8 ev1 = (q < 2) ? *(const short8*)(sb + evo[rt] + 32) : zf;
            #pragma unroll
            for (int ct = 0; ct < 2; ++ct) {
                acc[rt][ct] = __builtin_amdgcn_mfma_f32_16x16x32_bf16(sv0, wf[0][ct], acc[rt][ct], 0,0,0);
                acc[rt][ct] = __builtin_amdgcn_mfma_f32_16x16x32_bf16(sv1, wf[1][ct], acc[rt][ct], 0,0,0);
                acc[rt][ct] = __builtin_amdgcn_mfma_f32_16x16x32_bf16(nv0, wf[2][ct], acc[rt][ct], 0,0,0);
                acc[rt][ct] = __builtin_amdgcn_mfma_f32_16x16x32_bf16(nv1, wf[3][ct], acc[rt][ct], 0,0,0);
                acc[rt][ct] = __builtin_amdgcn_mfma_f32_16x16x32_bf16(ev0, wf[4][ct], acc[rt][ct], 0,0,0);
                acc[rt][ct] = __builtin_amdgcn_mfma_f32_16x16x32_bf16(ev1, wf[5][ct], acc[rt][ct], 0,0,0);
            }
        }

        if (MODE != 1) {
            #pragma unroll
            for (int ct=0; ct<2; ++ct)
                #pragma unroll
                for (int rt=0; rt<3; ++rt)
                    #pragma unroll
                    for (int r=0; r<4; ++r) {
                        float v = acc[rt][ct][r];
                        s_acc[ct] += v; s2_acc[ct] += v*v;
                    }
        }
        if (MODE == 2) {
            // gated pair store: row = b*48 + rt*16 + q*4 + r, pair pc = wave*16+l15
            // plain store: gpair transits LLC; k_gate reads it back cheaply.
            // (NT store costs +36MB WRITE_SIZE via partial-line write-through.)
            #pragma unroll
            for (int rt=0; rt<3; ++rt) {
                unsigned base = (unsigned)(b*48 + rt*16 + q*4)*64u + (unsigned)(wave*16 + l15);
                #pragma unroll
                for (int r=0; r<4; ++r)
                    gpair[base + (unsigned)r*64u] = packbf(acc[rt][0][r], acc[rt][1][r]);
            }
        }
        if (MODE == 1) {
            #pragma unroll
            for (int rt=0; rt<3; ++rt) {
                float part = 0.f;
                #pragma unroll
                for (int r=0; r<4; ++r) {
                    float f = acc[rt][0][r]*sc0 + sh0;
                    float g = acc[rt][1][r]*sc1 + sh1;
                    part += sigmoidf_(f) * softplusf_(g);
                }
                pb[(rt*4+q)*17 + l15] = part;
            }
            int a = lane >> 4, c16 = lane & 15;
            float s = pb[(3*a+0)*17 + c16] + pb[(3*a+1)*17 + c16] + pb[(3*a+2)*17 + c16];
            nsum[(b*4 + a)*AF + wave*16 + c16] = s;
            st2s += s; st2q += s*s;
        }

        if (k < 7) {
            short* db = &stg[(k + 1) & 1][0];
            #pragma unroll
            for (int s = 0; s < 3; ++s)
                if (kind[s] < 3) *(short8*)(db + ldso[s]) = hold[s];
        }
        __syncthreads();
    }

    if (MODE != 1) {
        #pragma unroll
        for (int ct=0; ct<2; ++ct) {
            float s = s_acc[ct], s2 = s2_acc[ct];
            s  += __shfl_xor(s, 16);  s  += __shfl_xor(s, 32);
            s2 += __shfl_xor(s2, 16); s2 += __shfl_xor(s2, 32);
            if (q == 0) {
                int c = ct ? cc : cf;
                atomicAdd(&stats1[c], s);
                atomicAdd(&stats1[128 + c], s2);
            }
        }
    } else {
        st2s += __shfl_xor(st2s, 16); st2s += __shfl_xor(st2s, 32);
        st2q += __shfl_xor(st2q, 16); st2q += __shfl_xor(st2q, 32);
        if (q == 0) {
            atomicAdd(&stats2[cf], st2s);
            atomicAdd(&stats2[64 + cf], st2q);
        }
    }
}

// -------- elementwise pass 2 (big-ws path): BN1 + sigmoid*softplus + m-sum --------
// block = 64 atoms (16 iters x 4 waves); thread = (wave-> atom slot, lane -> pair ch)
// BN1 scale/shift derived from stats1 per-thread (k_bn1fin folded in).
// Plain loads: gpair was just written -> LLC hits.
__global__ __launch_bounds__(256, 4)
void k_gate(const unsigned* __restrict__ gpair, const float* __restrict__ stats1,
            const float* __restrict__ g1, const float* __restrict__ b1,
            float* __restrict__ nsum, float* __restrict__ stats2)
{
    __shared__ float red[2][4][64];
    int tid = threadIdx.x;
    int lane = tid & 63, wave = tid >> 6;
    // filt channel = lane, core channel = 64+lane
    float mf = stats1[lane]       * (1.f/NMROW);
    float vf = stats1[128+lane]   * (1.f/NMROW) - mf*mf;
    float scf = g1[lane] * rsqrtf(vf + EPSBN);
    float shf = b1[lane] - mf*scf;
    float mc = stats1[64+lane]    * (1.f/NMROW);
    float vc = stats1[192+lane]   * (1.f/NMROW) - mc*mc;
    float scc = g1[64+lane] * rsqrtf(vc + EPSBN);
    float shc = b1[64+lane] - mc*scc;
    float st2s = 0.f, st2q = 0.f;
    int a0 = blockIdx.x*64 + wave;
    for (int j = 0; j < 16; ++j) {
        int atom = a0 + j*4;
        const unsigned* gp = gpair + (unsigned)atom*12u*64u + lane;
        unsigned u[12];
        #pragma unroll
        for (int i = 0; i < 12; ++i) u[i] = gp[i*64];
        float s = 0.f;
        #pragma unroll
        for (int i = 0; i < 12; ++i) {
            float f = __uint_as_float(u[i] << 16);
            float g = __uint_as_float(u[i] & 0xffff0000u);
            f = f*scf + shf;
            g = g*scc + shc;
            s += sigmoidf_(f) * softplusf_(g);
        }
        nsum[atom*AF + lane] = s;
        st2s += s; st2q += s*s;
    }
    red[0][wave][lane] = st2s;
    red[1][wave][lane] = st2q;
    __syncthreads();
    if (tid < 64) {
        float s  = red[0][0][tid] + red[0][1][tid] + red[0][2][tid] + red[0][3][tid];
        float s2 = red[1][0][tid] + red[1][1][tid] + red[1][2][tid] + red[1][3][tid];
        atomicAdd(&stats2[tid], s);
        atomicAdd(&stats2[64 + tid], s2);
    }
}

__global__ void k_bn1fin(const float* __restrict__ stats1, const float* __restrict__ g,
                         const float* __restrict__ b, float* __restrict__ bn1ss)
{
    int c = threadIdx.x;
    float mean = stats1[c] * (1.f/NMROW);
    float var  = stats1[128+c] * (1.f/NMROW) - mean*mean;
    float scale = g[c] * rsqrtf(var + EPSBN);
    bn1ss[c] = scale;
    bn1ss[128+c] = b[c] - mean*scale;
}

__global__ void k_update(float* __restrict__ afea, short* __restrict__ abf,
                         const float* __restrict__ nsum,
                         const float* __restrict__ stats2,
                         const float* __restrict__ g2, const float* __restrict__ b2)
{
    int g = blockIdx.x*256 + threadIdx.x;   // 16384 blocks
    int c = g & 63;
    float mean = stats2[c] * (1.f/NATOM);
    float var  = stats2[64+c] * (1.f/NATOM) - mean*mean;
    float scale = g2[c]*rsqrtf(var + EPSBN);
    float shift = b2[c] - mean*scale;
    float ns = nsum[g]*scale + shift;
    float a = afea[g];
    float v = softplusf_(a + ns) + a;       // afea == identity invariant
    afea[g] = v; abf[g] = f2bf(v);
}

__global__ void k_pool(const float* __restrict__ afea, const int* __restrict__ cidx,
                       float* __restrict__ pool, float* __restrict__ cnt)
{
    int g = blockIdx.x*256 + threadIdx.x;   // 1024 blocks
    int c = g & 63; int chunk = g >> 6;     // 4096 chunks x 16 atoms
    float run = 0.f, rc = 0.f; int cur = -1;
    for (int i = 0; i < 16; ++i) {
        int a = chunk*16 + i;
        int cr = cidx[a];
        float v = afea[a*64 + c];
        if (cr != cur) {
            if (cur >= 0) { atomicAdd(&pool[cur*64+c], run); if (c==0) atomicAdd(&cnt[cur], rc); }
            run = 0.f; rc = 0.f; cur = cr;
        }
        run += v; rc += 1.f;
    }
    atomicAdd(&pool[cur*64+c], run); if (c==0) atomicAdd(&cnt[cur], rc);
}

__global__ void k_head(const float* __restrict__ pool, const float* __restrict__ cnt,
                       const float* __restrict__ fc1w, const float* __restrict__ fc1b,
                       const float* __restrict__ o1w, const float* __restrict__ o1b,
                       const float* __restrict__ o2w, const float* __restrict__ o2b,
                       float* __restrict__ dout)
{
    __shared__ float spv[64], crys[128], h1[64];
    int b = blockIdx.x, tid = threadIdx.x;
    if (tid < 64) {
        float ct = fmaxf(cnt[b], 1.f);
        spv[tid] = softplusf_(pool[b*64+tid] / ct);
    }
    __syncthreads();
    float a = fc1b[tid];
    for (int k = 0; k < 64; ++k) a += spv[k] * fc1w[k*128 + tid];
    float v = softplusf_(a);
    crys[tid] = v;
    dout[NCRYS + b*128 + tid] = v;
    __syncthreads();
    if (tid < 64) {
        float a2 = o1b[tid];
        for (int k = 0; k < 128; ++k) a2 += crys[k] * o1w[k*64 + tid];
        h1[tid] = softplusf_(a2) * o2w[tid];
    }
    __syncthreads();
    if (tid == 0) {
        float s = o2b[0];
        for (int j = 0; j < 64; ++j) s += h1[j];
        dout[b] = s;
    }
}

extern "C" void kernel_launch(void* const* d_in, const int* in_sizes, int n_in,
                              void* d_out, int out_size, void* d_ws, size_t ws_size,
                              hipStream_t stream)
{
    const float* atom_fea = (const float*)d_in[0];
    const float* nbr_fea  = (const float*)d_in[1];
    const int*   nbr_idx  = (const int*)d_in[2];
    const int*   cidx     = (const int*)d_in[3];
    const float* emb_w    = (const float*)d_in[4];
    const float* emb_b    = (const float*)d_in[5];
    const float* cfw      = (const float*)d_in[6];
    const float* cfb      = (const float*)d_in[7];
    const float* bn1g     = (const float*)d_in[8];
    const float* bn1b     = (const float*)d_in[9];
    const float* bn2g     = (const float*)d_in[10];
    const float* bn2b     = (const float*)d_in[11];
    const float* fc1w     = (const float*)d_in[12];
    const float* fc1b     = (const float*)d_in[13];
    const float* o1w      = (const float*)d_in[14];
    const float* o1b      = (const float*)d_in[15];
    const float* o2w      = (const float*)d_in[16];
    const float* o2b      = (const float*)d_in[17];

    float* ws    = (float*)d_ws;
    float* afea  = ws;                         // 16 MB
    float* nsum  = ws + 4194304;               // 16 MB
    short* abf   = (short*)(ws + 8388608);     // 8 MB
    short* nbf   = (short*)(ws + 10485760);    // 75.5 MB
    short* wt2   = (short*)(ws + 29360128);    // 48 KB
    float* stats = ws + 29372416;              // 3 x 640
    float* pool  = ws + 29374336;              // 256 KB
    float* cnt   = ws + 29439872;              // 4 KB
    unsigned* gpair = (unsigned*)(ws + 29440896); // 201 MB (big-ws path only)

    bool big = ws_size >= (size_t)(29440896 + 50331648) * 4;

    hipMemsetAsync(stats, 0, (1920 + 65536 + 1024)*sizeof(float), stream);

    k_prep_nbr<<<(NMROW*6)/256, 256, 0, stream>>>(nbr_fea, nbf);
    k_embed<<<2048, 256, 0, stream>>>(atom_fea, emb_w, emb_b, afea, abf);

    for (int L = 0; L < 3; ++L) {
        float* st1 = stats + L*640;
        float* ss  = st1 + 256;
        float* st2 = st1 + 512;
        k_prep_w<<<96, 256, 0, stream>>>(cfw + L*169*128, wt2);
        if (big) {
            k_conv<2><<<CGRID, 256, 0, stream>>>(abf, nbf, nbr_idx, wt2, cfb + L*128,
                                                 st1, nullptr, nullptr, nullptr, gpair);
            k_gate<<<NATOM/64, 256, 0, stream>>>(gpair, st1, bn1g + L*128, bn1b + L*128,
                                                 nsum, st2);
        } else {
            k_conv<0><<<CGRID, 256, 0, stream>>>(abf, nbf, nbr_idx, wt2, cfb + L*128,
                                                 st1, nullptr, nullptr, nullptr, nullptr);
            k_bn1fin<<<1, 128, 0, stream>>>(st1, bn1g + L*128, bn1b + L*128, ss);
            k_conv<1><<<CGRID, 256, 0, stream>>>(abf, nbf, nbr_idx, wt2, cfb + L*128,
                                                 nullptr, ss, nsum, st2, nullptr);
        }
        k_update<<<16384, 256, 0, stream>>>(afea, abf, nsum, st2, bn2g + L*64, bn2b + L*64);
    }
    k_pool<<<1024, 256, 0, stream>>>(afea, cidx, pool, cnt);
    k_head<<<NCRYS, 128, 0, stream>>>(pool, cnt, fc1w, fc1b, o1w, o1b, o2w, o2b, (float*)d_out);
}